// Round 14
// baseline (71.378 us; speedup 1.0000x reference)
//
#include <hip/hip_runtime.h>
#include <stdint.h>

// Problem dims (fixed by reference setup_inputs)
#define NNODES 20000
#define NSRC   2048
#define DIN    128
#define NTILE  250        // row tiles of 80 (exact: 250*80 = 20000)
#define TW     5          // waves per block (80 rows / 16)

typedef short s16x8 __attribute__((ext_vector_type(8)));
typedef unsigned short u16x8 __attribute__((ext_vector_type(8)));
typedef float f32x4 __attribute__((ext_vector_type(4)));

// round-to-nearest-even f32 -> bf16 bits
static __device__ __forceinline__ unsigned short f2bf(float f) {
  union { float f; unsigned int u; } v; v.f = f;
  unsigned int r = v.u + 0x7FFFu + ((v.u >> 16) & 1u);
  return (unsigned short)(r >> 16);
}

static __device__ __forceinline__ float bf2f(unsigned short u) {
  union { unsigned int u; float f; } v; v.u = ((unsigned int)u) << 16;
  return v.f;
}

static __device__ __forceinline__ s16x8 pack8(float4 a, float4 b) {
  s16x8 r;
  r[0] = (short)f2bf(a.x); r[1] = (short)f2bf(a.y);
  r[2] = (short)f2bf(a.z); r[3] = (short)f2bf(a.w);
  r[4] = (short)f2bf(b.x); r[5] = (short)f2bf(b.y);
  r[6] = (short)f2bf(b.z); r[7] = (short)f2bf(b.w);
  return r;
}

static __device__ __forceinline__ s16x8 load_cvt8(const float* __restrict__ p) {
  return pack8(*reinterpret_cast<const float4*>(p),
               *reinterpret_cast<const float4*>(p + 4));
}

#define GLL16(g, l)                                                          \
  __builtin_amdgcn_global_load_lds(                                          \
      (const __attribute__((address_space(1))) void*)(g),                    \
      (__attribute__((address_space(3))) void*)(l), 16, 0, 0)

// ---------------------------------------------------------------------------
// Kernel 1: support = x[src_idx] @ W, written in MFMA-fragment-linear order:
// supTp[((kk*8+n)*64+lane)*8+e] = bf16(support[kk*32+(lane>>4)*8+e][n*16+(lane&15)])
// (validated R7-R13)
// ---------------------------------------------------------------------------
__global__ __launch_bounds__(128) void support_kernel(
    const float* __restrict__ x, const float* __restrict__ W,
    const int* __restrict__ src_idx, unsigned short* __restrict__ supTp) {
  __shared__ float xrows[8][DIN];
  const int j = threadIdx.x;
  const int s0 = blockIdx.x * 8;
#pragma unroll
  for (int i = 0; i < 8; ++i) {
    const int src = src_idx[s0 + i];
    xrows[i][j] = x[(size_t)src * DIN + j];
  }
  __syncthreads();
  float acc[8];
#pragma unroll
  for (int i = 0; i < 8; ++i) acc[i] = 0.f;
  for (int k = 0; k < DIN; ++k) {
    const float w = W[(size_t)k * DIN + j];
#pragma unroll
    for (int i = 0; i < 8; ++i) acc[i] += xrows[i][k] * w;
  }
  u16x8 o;
#pragma unroll
  for (int i = 0; i < 8; ++i) o[i] = f2bf(acc[i]);
  const int kk = s0 >> 5;
  const int g2 = (s0 >> 3) & 3;
  const int n = j >> 4;
  const int lane = (j & 15) + g2 * 16;
  *reinterpret_cast<u16x8*>(&supTp[(size_t)((kk * 8 + n) * 64 + lane) * 8]) = o;
}

// ---------------------------------------------------------------------------
// Kernel 2: split-K partial GEMM. Block (tile, half): 80 rows x K=1024 half.
// Grid 500 (~2/CU, worst-CU bytes 1.15 MB — halves R13's 2.3 MB). Pipeline
// structure = R13 verbatim: dbuf LDS, line-contiguous gll, src-swizzled A,
// fragment-linear B, counted vmcnt (never 0 in loop), chunk-offset
// decorrelation. Partials -> ws in C-fragment-linear bf16 (coalesced 8B/lane).
// MFMA 16x16x32 bf16 layouts (validated R2-R13):
//   A-frag: lane l holds A[l&15][(l>>4)*8+e]; B-frag: B[(l>>4)*8+e][l&15]
//   C/D:    lane l holds C[(l>>4)*4+r][l&15]
// ---------------------------------------------------------------------------
__global__ __launch_bounds__(320) void splitk_kernel(
    const float* __restrict__ A,             // [NNODES][NSRC] f32
    const unsigned short* __restrict__ supTp,// fragment-packed, 512 KB
    unsigned short* __restrict__ pws) {      // partials, frag-linear bf16
  const int tid = threadIdx.x;
  const int lane = tid & 63;
  const int w = tid >> 6;                    // 0..4
  const int r16 = lane & 15;
  const int g = lane >> 4;
  const int bid = blockIdx.x;
  const int tile = bid >> 1;
  const int half = bid & 1;
  const int rowBase = tile * 80;
  const int off = bid & 15;                  // chunk-start decorrelation

  // Ap [2][80*64] f32 = 40 KB | Bp [2][8192] u16 = 32 KB  (72 KB, 2 blk/CU)
  __shared__ __attribute__((aligned(16))) unsigned char pool[73728];
  float* Ap = (float*)pool;
  unsigned short* Bp = (unsigned short*)(pool + 40960);

  f32x4 acc[8];
#pragma unroll
  for (int n = 0; n < 8; ++n) acc[n] = (f32x4){0.f, 0.f, 0.f, 0.f};

  const int wu = __builtin_amdgcn_readfirstlane(w);

  // STAGE chunk cc (cols half*1024 + cc*64 ..+63) into buffer `buf`.
  // A: i2 0..3 -> local rows w*16+i2*4..+3 (4 x 256B segs), src slot
  //    pre-swizzled slot^(row&7) (involution; read undoes it).
  // B: waves 0-3, iB = w*4+i2: 64 lanes x 16B contiguous 1KB (frag-linear).
#define STAGE(buf, cc)                                                        \
  {                                                                           \
    _Pragma("unroll") for (int i2 = 0; i2 < 4; ++i2) {                        \
      const int row = w * 16 + i2 * 4 + (lane >> 4);                          \
      GLL16(A + (size_t)(rowBase + row) * NSRC + half * 1024 + (cc) * 64 +    \
                (((lane & 15) ^ (row & 7)) << 2),                             \
            Ap + (buf) * 5120 + w * 1024 + i2 * 256);                         \
    }                                                                         \
    if (wu < 4) {                                                             \
      _Pragma("unroll") for (int i2 = 0; i2 < 4; ++i2) {                      \
        const int iB = w * 4 + i2;                                            \
        const int C = half * 16 + (cc);                                       \
        GLL16(supTp +                                                         \
                  ((size_t)((C * 2 + (iB >> 3)) * 8 + (iB & 7)) * 64 + lane)  \
                      * 8,                                                    \
              Bp + (buf) * 8192 + iB * 512);                                  \
      }                                                                       \
    }                                                                         \
  }

#define COMPUTE(buf)                                                          \
  {                                                                           \
    _Pragma("unroll") for (int kk2 = 0; kk2 < 2; ++kk2) {                     \
      const float* rb = Ap + (buf) * 5120 + (w * 16 + r16) * 64;              \
      const float4 lo = *reinterpret_cast<const float4*>(                     \
          &rb[((kk2 * 8 + g * 2) ^ (r16 & 7)) << 2]);                         \
      const float4 hi = *reinterpret_cast<const float4*>(                     \
          &rb[((kk2 * 8 + g * 2 + 1) ^ (r16 & 7)) << 2]);                     \
      const s16x8 a = pack8(lo, hi);                                          \
      _Pragma("unroll") for (int n = 0; n < 8; ++n) {                         \
        const s16x8 b = *reinterpret_cast<const s16x8*>(                      \
            &Bp[(buf) * 8192 + ((kk2 * 8 + n) * 64 + lane) * 8]);             \
        acc[n] =                                                              \
            __builtin_amdgcn_mfma_f32_16x16x32_bf16(a, b, acc[n], 0, 0, 0);   \
      }                                                                       \
    }                                                                         \
  }

  STAGE(0, off);
  for (int c = 0; c < 15; ++c) {
    const int cnext = (c + 1 + off) & 15;
    STAGE((c & 1) ^ 1, cnext);
    if (wu < 4) {
      asm volatile("s_waitcnt vmcnt(8)" ::: "memory");  // chunk c arrived
    } else {
      asm volatile("s_waitcnt vmcnt(4)" ::: "memory");  // wave 4: A only
    }
    __builtin_amdgcn_s_barrier();
    COMPUTE(c & 1);
    __builtin_amdgcn_s_barrier();
  }
  asm volatile("s_waitcnt vmcnt(0)" ::: "memory");
  __builtin_amdgcn_s_barrier();
  COMPUTE(1);  // chunk 15 -> buffer 1

  // partial store: bf16, C-fragment-linear; 8B/lane coalesced (512B/instr)
#pragma unroll
  for (int n = 0; n < 8; ++n) {
    ushort4 v;
    v.x = f2bf(acc[n][0]); v.y = f2bf(acc[n][1]);
    v.z = f2bf(acc[n][2]); v.w = f2bf(acc[n][3]);
    const size_t idx =
        ((((size_t)half * NTILE + tile) * TW + w) * 8 + n) * 64 + lane;
    *reinterpret_cast<ushort4*>(&pws[idx * 4]) = v;
  }
}

// ---------------------------------------------------------------------------
// Kernel 3: combine halves + LeakyReLU + GEMM2 (validated R13 epilogue) + out.
// Grid 250 x 320 thr; wave w owns rows tile*80 + w*16..+15.
// ---------------------------------------------------------------------------
__global__ __launch_bounds__(320) void combine_kernel(
    const unsigned short* __restrict__ pws,  // partials
    const float* __restrict__ Wd,            // dense0_w [DIN][DIN] f32
    float* __restrict__ out) {               // [NNODES][DIN] f32
  const int tid = threadIdx.x;
  const int lane = tid & 63;
  const int w = tid >> 6;
  const int r16 = lane & 15;
  const int g = lane >> 4;
  const int tile = blockIdx.x;
  const int rowBase = tile * 80;

  __shared__ unsigned short act[TW][16 * 136];
  unsigned short* actw = act[w];

#pragma unroll
  for (int n = 0; n < 8; ++n) {
    const size_t i0 = (((size_t)0 * NTILE + tile) * TW + w) * 8 + n;
    const size_t i1 = (((size_t)1 * NTILE + tile) * TW + w) * 8 + n;
    const ushort4 h0 = *reinterpret_cast<const ushort4*>(&pws[(i0 * 64 + lane) * 4]);
    const ushort4 h1 = *reinterpret_cast<const ushort4*>(&pws[(i1 * 64 + lane) * 4]);
    float v0 = bf2f(h0.x) + bf2f(h1.x);
    float v1 = bf2f(h0.y) + bf2f(h1.y);
    float v2 = bf2f(h0.z) + bf2f(h1.z);
    float v3 = bf2f(h0.w) + bf2f(h1.w);
    v0 = (v0 >= 0.f) ? v0 : 0.01f * v0;
    v1 = (v1 >= 0.f) ? v1 : 0.01f * v1;
    v2 = (v2 >= 0.f) ? v2 : 0.01f * v2;
    v3 = (v3 >= 0.f) ? v3 : 0.01f * v3;
    actw[(g * 4 + 0) * 136 + n * 16 + r16] = f2bf(v0);
    actw[(g * 4 + 1) * 136 + n * 16 + r16] = f2bf(v1);
    actw[(g * 4 + 2) * 136 + n * 16 + r16] = f2bf(v2);
    actw[(g * 4 + 3) * 136 + n * 16 + r16] = f2bf(v3);
  }
  // own-wave write->read; compiler orders via lgkmcnt

  f32x4 acc2[8];
#pragma unroll
  for (int n = 0; n < 8; ++n) acc2[n] = (f32x4){0.f, 0.f, 0.f, 0.f};
#pragma unroll
  for (int k2 = 0; k2 < 4; ++k2) {
    const int k = k2 * 32 + g * 8;
    const s16x8 a2 = *reinterpret_cast<const s16x8*>(&actw[r16 * 136 + k]);
#pragma unroll
    for (int n = 0; n < 8; ++n) {
      const s16x8 b2 = load_cvt8(Wd + (size_t)(n * 16 + r16) * DIN + k);
      acc2[n] =
          __builtin_amdgcn_mfma_f32_16x16x32_bf16(a2, b2, acc2[n], 0, 0, 0);
    }
  }
#pragma unroll
  for (int n = 0; n < 8; ++n)
#pragma unroll
    for (int r = 0; r < 4; ++r)
      out[(size_t)(rowBase + w * 16 + g * 4 + r) * DIN + n * 16 + r16] =
          acc2[n][r];
}

// ---------------------------------------------------------------------------
extern "C" void kernel_launch(void* const* d_in, const int* in_sizes, int n_in,
                              void* d_out, int out_size, void* d_ws, size_t ws_size,
                              hipStream_t stream) {
  const float* x   = (const float*)d_in[0];   // [20000][128]
  const float* A   = (const float*)d_in[1];   // [20000][2048]
  const float* W   = (const float*)d_in[2];   // [128][128]
  const float* Wd  = (const float*)d_in[3];   // [128][128]
  const int*   src = (const int*)d_in[4];     // [2048]
  float* out = (float*)d_out;

  unsigned short* supTp = (unsigned short*)d_ws;             // 512 KB
  unsigned short* pws = (unsigned short*)((char*)d_ws + 524288);  // 10.24 MB

  support_kernel<<<NSRC / 8, 128, 0, stream>>>(x, W, src, supTp);
  splitk_kernel<<<NTILE * 2, 320, 0, stream>>>(A, supTp, pws);
  combine_kernel<<<NTILE, 320, 0, stream>>>(pws, Wd, out);
}

// Round 15
// 66.605 us; speedup vs baseline: 1.0717x; 1.0717x over previous
//
#include <hip/hip_runtime.h>
#include <stdint.h>

// Problem dims (fixed by reference setup_inputs)
#define NNODES 20000
#define NSRC   2048
#define DIN    128
#define BM     80          // rows per block (5 waves x 16); grid 250 = 1/CU

typedef short s16x8 __attribute__((ext_vector_type(8)));
typedef unsigned short u16x8 __attribute__((ext_vector_type(8)));
typedef float f32x4 __attribute__((ext_vector_type(4)));

// round-to-nearest-even f32 -> bf16 bits
static __device__ __forceinline__ unsigned short f2bf(float f) {
  union { float f; unsigned int u; } v; v.f = f;
  unsigned int r = v.u + 0x7FFFu + ((v.u >> 16) & 1u);
  return (unsigned short)(r >> 16);
}

static __device__ __forceinline__ s16x8 pack8(float4 a, float4 b) {
  s16x8 r;
  r[0] = (short)f2bf(a.x); r[1] = (short)f2bf(a.y);
  r[2] = (short)f2bf(a.z); r[3] = (short)f2bf(a.w);
  r[4] = (short)f2bf(b.x); r[5] = (short)f2bf(b.y);
  r[6] = (short)f2bf(b.z); r[7] = (short)f2bf(b.w);
  return r;
}

static __device__ __forceinline__ s16x8 load_cvt8(const float* __restrict__ p) {
  return pack8(*reinterpret_cast<const float4*>(p),
               *reinterpret_cast<const float4*>(p + 4));
}

#define GLL16(g, l)                                                          \
  __builtin_amdgcn_global_load_lds(                                          \
      (const __attribute__((address_space(1))) void*)(g),                    \
      (__attribute__((address_space(3))) void*)(l), 16, 0, 0)

// ---------------------------------------------------------------------------
// Kernel 1: support = x[src_idx] @ W, written in MFMA-fragment-linear order:
// supTp[((kk*8+n)*64+lane)*8+e] = bf16(support[kk*32+(lane>>4)*8+e][n*16+(lane&15)])
// (validated R7-R14)
// ---------------------------------------------------------------------------
__global__ __launch_bounds__(128) void support_kernel(
    const float* __restrict__ x, const float* __restrict__ W,
    const int* __restrict__ src_idx, unsigned short* __restrict__ supTp) {
  __shared__ float xrows[8][DIN];
  const int j = threadIdx.x;
  const int s0 = blockIdx.x * 8;
#pragma unroll
  for (int i = 0; i < 8; ++i) {
    const int src = src_idx[s0 + i];
    xrows[i][j] = x[(size_t)src * DIN + j];
  }
  __syncthreads();
  float acc[8];
#pragma unroll
  for (int i = 0; i < 8; ++i) acc[i] = 0.f;
  for (int k = 0; k < DIN; ++k) {
    const float w = W[(size_t)k * DIN + j];
#pragma unroll
    for (int i = 0; i < 8; ++i) acc[i] += xrows[i][k] * w;
  }
  u16x8 o;
#pragma unroll
  for (int i = 0; i < 8; ++i) o[i] = f2bf(acc[i]);
  const int kk = s0 >> 5;
  const int g2 = (s0 >> 3) & 3;
  const int n = j >> 4;
  const int lane = (j & 15) + g2 * 16;
  *reinterpret_cast<u16x8*>(&supTp[(size_t)((kk * 8 + n) * 64 + lane) * 8]) = o;
}

// ---------------------------------------------------------------------------
// Kernel 2: out = LeakyReLU(A @ support) @ dense0_w^T
// R15 = R9 (1 block/CU, min delivered bytes: A 164MB + B 128MB) + PIPELINE
// DEPTH 3: quad-buffered LDS (4 x 36KB = 144KB of the 160KB pool), 3 chunks
// in flight (108KB/CU >> latency-BW product), counted vmcnt(24)/(12) steady
// state + explicit 3-step drain. Chunk-offset decorrelation retained (R13 +7%).
// Staging geometry, swizzle, fragment math, epilogue = validated R9/R13 code.
// MFMA 16x16x32 bf16 layouts (validated R2-R14):
//   A-frag: lane l holds A[l&15][(l>>4)*8+e]; B-frag: B[(l>>4)*8+e][l&15]
//   C/D:    lane l holds C[(l>>4)*4+r][l&15]
// ---------------------------------------------------------------------------
__global__ __launch_bounds__(320) void fused_gcn_kernel(
    const float* __restrict__ A,             // [NNODES][NSRC] f32
    const unsigned short* __restrict__ supTp,// fragment-packed, 512 KB
    const float* __restrict__ Wd,            // dense0_w [DIN][DIN] f32
    float* __restrict__ out) {               // [NNODES][DIN] f32
  const int tid = threadIdx.x;
  const int lane = tid & 63;
  const int w = tid >> 6;                    // wave 0..4
  const int r16 = lane & 15;
  const int g = lane >> 4;
  const int rowBase = blockIdx.x * BM;
  const int off = blockIdx.x & 31;           // chunk-start decorrelation

  // pool: Ap 4 x [80*64] f32 = 80 KB | Bp 4 x [8192] u16 = 64 KB  -> 144 KB
  // (1 block/CU regardless, so the big LDS costs nothing.)
  __shared__ __attribute__((aligned(16))) unsigned char pool[147456];
  float* Ap = (float*)pool;
  unsigned short* Bp = (unsigned short*)(pool + 81920);

  f32x4 acc[8];
#pragma unroll
  for (int n = 0; n < 8; ++n) acc[n] = (f32x4){0.f, 0.f, 0.f, 0.f};

  const int wu = __builtin_amdgcn_readfirstlane(w);

  // STAGE chunk index cc (cols cc*64..+63) into LDS buffer `buf` (0..3).
  // A: i2 0..3 -> local rows w*16+i2*4..+3 (4 x 256B segs); source slot
  //    pre-swizzled slot^(row&7) (involution; swizzled read undoes it).
  // B: waves 0-3, iB = w*4+i2: 64 lanes x 16B contiguous 1KB (frag-linear).
#define STAGE(buf, cc)                                                        \
  {                                                                           \
    _Pragma("unroll") for (int i2 = 0; i2 < 4; ++i2) {                        \
      const int row = w * 16 + i2 * 4 + (lane >> 4);                          \
      GLL16(A + (size_t)(rowBase + row) * NSRC + (cc) * 64 +                  \
                (((lane & 15) ^ (row & 7)) << 2),                             \
            Ap + (buf) * 5120 + w * 1024 + i2 * 256);                         \
    }                                                                         \
    if (wu < 4) {                                                             \
      _Pragma("unroll") for (int i2 = 0; i2 < 4; ++i2) {                      \
        const int iB = w * 4 + i2;                                            \
        GLL16(supTp +                                                         \
                  ((size_t)(((cc) * 2 + (iB >> 3)) * 8 + (iB & 7)) * 64 +     \
                   lane) * 8,                                                 \
              Bp + (buf) * 8192 + iB * 512);                                  \
      }                                                                       \
    }                                                                         \
  }

#define COMPUTE(buf)                                                          \
  {                                                                           \
    _Pragma("unroll") for (int kk2 = 0; kk2 < 2; ++kk2) {                     \
      const float* rb = Ap + (buf) * 5120 + (w * 16 + r16) * 64;              \
      const float4 lo = *reinterpret_cast<const float4*>(                     \
          &rb[((kk2 * 8 + g * 2) ^ (r16 & 7)) << 2]);                         \
      const float4 hi = *reinterpret_cast<const float4*>(                     \
          &rb[((kk2 * 8 + g * 2 + 1) ^ (r16 & 7)) << 2]);                     \
      const s16x8 a = pack8(lo, hi);                                          \
      _Pragma("unroll") for (int n = 0; n < 8; ++n) {                         \
        const s16x8 b = *reinterpret_cast<const s16x8*>(                      \
            &Bp[(buf) * 8192 + ((kk2 * 8 + n) * 64 + lane) * 8]);             \
        acc[n] =                                                              \
            __builtin_amdgcn_mfma_f32_16x16x32_bf16(a, b, acc[n], 0, 0, 0);   \
      }                                                                       \
    }                                                                         \
  }

#define PERM(i) (((i) + off) & 31)

  // prologue: 3 chunks in flight
  STAGE(0, PERM(0));
  STAGE(1, PERM(1));
  STAGE(2, PERM(2));
  // steady state: issue chunk c+3, wait for chunk c (3 chunks = 24/12 newer
  // gll stay outstanding), compute.
  for (int c = 0; c < 29; ++c) {
    STAGE((c + 3) & 3, PERM(c + 3));
    if (wu < 4) {
      asm volatile("s_waitcnt vmcnt(24)" ::: "memory");
    } else {
      asm volatile("s_waitcnt vmcnt(12)" ::: "memory");
    }
    __builtin_amdgcn_s_barrier();
    COMPUTE(c & 3);
    __builtin_amdgcn_s_barrier();
  }
  // drain: chunks 29,30,31 (no further staging)
  if (wu < 4) { asm volatile("s_waitcnt vmcnt(16)" ::: "memory"); }
  else        { asm volatile("s_waitcnt vmcnt(8)"  ::: "memory"); }
  __builtin_amdgcn_s_barrier();
  COMPUTE(29 & 3);
  __builtin_amdgcn_s_barrier();
  if (wu < 4) { asm volatile("s_waitcnt vmcnt(8)" ::: "memory"); }
  else        { asm volatile("s_waitcnt vmcnt(4)" ::: "memory"); }
  __builtin_amdgcn_s_barrier();
  COMPUTE(30 & 3);
  __builtin_amdgcn_s_barrier();
  asm volatile("s_waitcnt vmcnt(0)" ::: "memory");
  __builtin_amdgcn_s_barrier();
  COMPUTE(31 & 3);

  // ---- epilogue: LeakyReLU -> act (reuse pool) -> GEMM2 -> store ----------
  __builtin_amdgcn_s_barrier();  // all MFMA ds_reads retired; pool reusable
  unsigned short* actw = (unsigned short*)pool + w * 2176;  // [16][136]
#pragma unroll
  for (int n = 0; n < 8; ++n)
#pragma unroll
    for (int r = 0; r < 4; ++r) {
      float v = acc[n][r];
      v = (v >= 0.f) ? v : 0.01f * v;
      actw[(g * 4 + r) * 136 + n * 16 + r16] = f2bf(v);
    }
  // own-wave write->read; compiler orders via lgkmcnt

  f32x4 acc2[8];
#pragma unroll
  for (int n = 0; n < 8; ++n) acc2[n] = (f32x4){0.f, 0.f, 0.f, 0.f};
#pragma unroll
  for (int k2 = 0; k2 < 4; ++k2) {
    const int k = k2 * 32 + g * 8;
    const s16x8 a2 = *reinterpret_cast<const s16x8*>(&actw[r16 * 136 + k]);
#pragma unroll
    for (int n = 0; n < 8; ++n) {
      const s16x8 b2 = load_cvt8(Wd + (size_t)(n * 16 + r16) * DIN + k);
      acc2[n] =
          __builtin_amdgcn_mfma_f32_16x16x32_bf16(a2, b2, acc2[n], 0, 0, 0);
    }
  }
#pragma unroll
  for (int n = 0; n < 8; ++n)
#pragma unroll
    for (int r = 0; r < 4; ++r)
      out[(size_t)(rowBase + w * 16 + g * 4 + r) * DIN + n * 16 + r16] =
          acc2[n][r];
}

// ---------------------------------------------------------------------------
extern "C" void kernel_launch(void* const* d_in, const int* in_sizes, int n_in,
                              void* d_out, int out_size, void* d_ws, size_t ws_size,
                              hipStream_t stream) {
  const float* x   = (const float*)d_in[0];   // [20000][128]
  const float* A   = (const float*)d_in[1];   // [20000][2048]
  const float* W   = (const float*)d_in[2];   // [128][128]
  const float* Wd  = (const float*)d_in[3];   // [128][128]
  const int*   src = (const int*)d_in[4];     // [2048]
  float* out = (float*)d_out;

  unsigned short* supTp = (unsigned short*)d_ws;  // 512 KB, fragment-packed

  support_kernel<<<NSRC / 8, 128, 0, stream>>>(x, W, src, supTp);
  fused_gcn_kernel<<<NNODES / BM, 320, 0, stream>>>(A, supTp, Wd, out);
}

// Round 16
// 60.747 us; speedup vs baseline: 1.1750x; 1.0964x over previous
//
#include <hip/hip_runtime.h>
#include <stdint.h>

// Problem dims (fixed by reference setup_inputs)
#define NNODES 20000
#define NSRC   2048
#define DIN    128

typedef short s16x8 __attribute__((ext_vector_type(8)));
typedef unsigned short u16x8 __attribute__((ext_vector_type(8)));
typedef float f32x4 __attribute__((ext_vector_type(4)));

// round-to-nearest-even f32 -> bf16 bits
static __device__ __forceinline__ unsigned short f2bf(float f) {
  union { float f; unsigned int u; } v; v.f = f;
  unsigned int r = v.u + 0x7FFFu + ((v.u >> 16) & 1u);
  return (unsigned short)(r >> 16);
}

static __device__ __forceinline__ s16x8 pack8(float4 a, float4 b) {
  s16x8 r;
  r[0] = (short)f2bf(a.x); r[1] = (short)f2bf(a.y);
  r[2] = (short)f2bf(a.z); r[3] = (short)f2bf(a.w);
  r[4] = (short)f2bf(b.x); r[5] = (short)f2bf(b.y);
  r[6] = (short)f2bf(b.z); r[7] = (short)f2bf(b.w);
  return r;
}

static __device__ __forceinline__ s16x8 load_cvt8(const float* __restrict__ p) {
  return pack8(*reinterpret_cast<const float4*>(p),
               *reinterpret_cast<const float4*>(p + 4));
}

#define GLL16(g, l)                                                          \
  __builtin_amdgcn_global_load_lds(                                          \
      (const __attribute__((address_space(1))) void*)(g),                    \
      (__attribute__((address_space(3))) void*)(l), 16, 0, 0)

// ---------------------------------------------------------------------------
// Kernel 1: support = x[src_idx] @ W, written DIRECTLY in MFMA-fragment-linear
// order: supTp[((kk*8 + n)*64 + lane)*8 + e] = bf16(support[kk*32 + (lane>>4)*8
// + e][n*16 + (lane&15)]).  (validated R7-R15)
// ---------------------------------------------------------------------------
__global__ __launch_bounds__(128) void support_kernel(
    const float* __restrict__ x, const float* __restrict__ W,
    const int* __restrict__ src_idx, unsigned short* __restrict__ supTp) {
  __shared__ float xrows[8][DIN];
  const int j = threadIdx.x;           // output feature 0..127
  const int s0 = blockIdx.x * 8;       // first source (k-index) of this block
#pragma unroll
  for (int i = 0; i < 8; ++i) {
    const int src = src_idx[s0 + i];
    xrows[i][j] = x[(size_t)src * DIN + j];
  }
  __syncthreads();
  float acc[8];
#pragma unroll
  for (int i = 0; i < 8; ++i) acc[i] = 0.f;
  for (int k = 0; k < DIN; ++k) {
    const float w = W[(size_t)k * DIN + j];   // coalesced across threads
#pragma unroll
    for (int i = 0; i < 8; ++i) acc[i] += xrows[i][k] * w;  // LDS broadcast
  }
  u16x8 o;
#pragma unroll
  for (int i = 0; i < 8; ++i) o[i] = f2bf(acc[i]);
  const int kk = s0 >> 5;              // 32-wide k-chunk
  const int g2 = (s0 >> 3) & 3;        // k-slot group within chunk
  const int n = j >> 4;                // n-tile
  const int lane = (j & 15) + g2 * 16; // MFMA lane holding these 8 elements
  *reinterpret_cast<u16x8*>(&supTp[(size_t)((kk * 8 + n) * 64 + lane) * 8]) = o;
}

// ---------------------------------------------------------------------------
// Kernel 2: out = LeakyReLU(A @ support) @ dense0_w^T
// TERMINAL CONFIG (R12, 60.7us validated): R7 pipeline + per-block
// chunk-offset decorrelation. Block = 128 thr / 2 waves; wave w owns rows
// rowBase + w*16..+15. Grid 625 (~2.4 blk/CU).
//   A: 8 gll/chunk (4 rows x 256B segs), XOR-slot-swizzled SOURCE (rule #21).
//   B: 16 gll/chunk, 1KB contiguous each (supTp fragment-linear).
// Sync: counted vmcnt(12) + raw s_barrier; never vmcnt(0) in loop.
// Decorrelation: block b iterates chunks (i + (b&31)) & 31 — spreads the
// instantaneous A-column / B-chunk working set across the address space.
// MFMA 16x16x32 bf16 layouts (validated R2-R15):
//   A-frag: lane l holds A[l&15][(l>>4)*8+e]; B-frag: B[(l>>4)*8+e][l&15]
//   C/D:    lane l holds C[(l>>4)*4+r][l&15]
// ---------------------------------------------------------------------------
__global__ __launch_bounds__(128) void fused_gcn_kernel(
    const float* __restrict__ A,             // [NNODES][NSRC] f32
    const unsigned short* __restrict__ supTp,// fragment-packed, 512 KB
    const float* __restrict__ Wd,            // dense0_w [DIN][DIN] f32
    float* __restrict__ out) {               // [NNODES][DIN] f32
  const int tid = threadIdx.x;
  const int lane = tid & 63;
  const int w = tid >> 6;                    // wave 0..1
  const int r16 = lane & 15;
  const int g = lane >> 4;
  const int rowBase = blockIdx.x * 32;
  const int off = blockIdx.x & 31;           // chunk-start decorrelation

  // pool: Ap [2][32 rows][64 f32] = 16 KB | Bp [2][2 kk][8 n][64 lane][8 e]
  // = 32 KB. After the K-loop (post-barrier) the first 8.7 KB are reused as
  // the per-wave act tiles.
  __shared__ __attribute__((aligned(16))) unsigned char pool[49152];
  float* Ap = (float*)pool;
  unsigned short* Bp = (unsigned short*)(pool + 16384);

  f32x4 acc[8];
#pragma unroll
  for (int n = 0; n < 8; ++n) acc[n] = (f32x4){0.f, 0.f, 0.f, 0.f};

  // ---- STAGE chunk cc (cols cc*64..+63) into buffer `buf` -----------------
  // A: instr i = w*4+i2 covers rows 4i..4i+3 (4 x 256B segments). Source col
  //    slot pre-swizzled: slot_src = (lane&15) ^ (row&7)  (involution).
  // B: instr iB = w*8+i2 -> (kk2=iB>>3, n=iB&7): 64 lanes x 16B contiguous.
#define STAGE(buf, cc)                                                        \
  {                                                                           \
    _Pragma("unroll") for (int i2 = 0; i2 < 4; ++i2) {                        \
      const int i = w * 4 + i2;                                               \
      const int row = 4 * i + (lane >> 4);                                    \
      GLL16(A + (size_t)(rowBase + row) * NSRC + (cc) * 64 +                  \
                (((lane & 15) ^ (row & 7)) << 2),                             \
            Ap + (buf) * 2048 + i * 256);                                     \
    }                                                                         \
    _Pragma("unroll") for (int i2 = 0; i2 < 8; ++i2) {                        \
      const int iB = w * 8 + i2;                                              \
      GLL16(supTp +                                                           \
                ((size_t)(((cc) * 2 + (iB >> 3)) * 8 + (iB & 7)) * 64 + lane) \
                    * 8,                                                      \
            Bp + (buf) * 8192 + iB * 512);                                    \
    }                                                                         \
  }

  // ---- COMPUTE chunk in buffer `buf` (per wave: rows w*16..+15) -----------
#define COMPUTE(buf)                                                          \
  {                                                                           \
    _Pragma("unroll") for (int kk2 = 0; kk2 < 2; ++kk2) {                     \
      const float* rb = Ap + (buf) * 2048 + (w * 16 + r16) * 64;              \
      const float4 lo = *reinterpret_cast<const float4*>(                     \
          &rb[((kk2 * 8 + g * 2) ^ (r16 & 7)) << 2]);                         \
      const float4 hi = *reinterpret_cast<const float4*>(                     \
          &rb[((kk2 * 8 + g * 2 + 1) ^ (r16 & 7)) << 2]);                     \
      const s16x8 a = pack8(lo, hi);                                          \
      _Pragma("unroll") for (int n = 0; n < 8; ++n) {                         \
        const s16x8 b = *reinterpret_cast<const s16x8*>(                      \
            &Bp[(buf) * 8192 + ((kk2 * 8 + n) * 64 + lane) * 8]);             \
        acc[n] =                                                              \
            __builtin_amdgcn_mfma_f32_16x16x32_bf16(a, b, acc[n], 0, 0, 0);   \
      }                                                                       \
    }                                                                         \
  }

  // prologue: stage first chunk of this block's permuted order
  STAGE(0, off);
  for (int c = 0; c < 31; ++c) {
    const int cnext = (c + 1 + off) & 31;
    STAGE((c & 1) ^ 1, cnext);
    asm volatile("s_waitcnt vmcnt(12)" ::: "memory");  // chunk c arrived
    __builtin_amdgcn_s_barrier();                      // all waves' staging in
    COMPUTE(c & 1);
    __builtin_amdgcn_s_barrier();                      // all reads done
  }
  asm volatile("s_waitcnt vmcnt(0)" ::: "memory");
  __builtin_amdgcn_s_barrier();
  COMPUTE(1);  // last chunk -> buffer 1

  // ---- epilogue: LeakyReLU -> act (reuse pool) -> GEMM2 -> store ----------
  __builtin_amdgcn_s_barrier();  // everyone's MFMA reads retired; pool free
  unsigned short* actw = (unsigned short*)pool + w * 2176;  // [16][136]
#pragma unroll
  for (int n = 0; n < 8; ++n)
#pragma unroll
    for (int r = 0; r < 4; ++r) {
      float v = acc[n][r];
      v = (v >= 0.f) ? v : 0.01f * v;
      actw[(g * 4 + r) * 136 + n * 16 + r16] = f2bf(v);
    }
  // own-wave write->read; compiler orders via lgkmcnt

  f32x4 acc2[8];
#pragma unroll
  for (int n = 0; n < 8; ++n) acc2[n] = (f32x4){0.f, 0.f, 0.f, 0.f};
#pragma unroll
  for (int k2 = 0; k2 < 4; ++k2) {
    const int k = k2 * 32 + g * 8;
    const s16x8 a2 = *reinterpret_cast<const s16x8*>(&actw[r16 * 136 + k]);
#pragma unroll
    for (int n = 0; n < 8; ++n) {
      const s16x8 b2 = load_cvt8(Wd + (size_t)(n * 16 + r16) * DIN + k);
      acc2[n] =
          __builtin_amdgcn_mfma_f32_16x16x32_bf16(a2, b2, acc2[n], 0, 0, 0);
    }
  }
#pragma unroll
  for (int n = 0; n < 8; ++n)
#pragma unroll
    for (int r = 0; r < 4; ++r)
      out[(size_t)(rowBase + w * 16 + g * 4 + r) * DIN + n * 16 + r16] =
          acc2[n][r];
}

// ---------------------------------------------------------------------------
extern "C" void kernel_launch(void* const* d_in, const int* in_sizes, int n_in,
                              void* d_out, int out_size, void* d_ws, size_t ws_size,
                              hipStream_t stream) {
  const float* x   = (const float*)d_in[0];   // [20000][128]
  const float* A   = (const float*)d_in[1];   // [20000][2048]
  const float* W   = (const float*)d_in[2];   // [128][128]
  const float* Wd  = (const float*)d_in[3];   // [128][128]
  const int*   src = (const int*)d_in[4];     // [2048]
  float* out = (float*)d_out;

  unsigned short* supTp = (unsigned short*)d_ws;  // 512 KB, fragment-packed

  support_kernel<<<NSRC / 8, 128, 0, stream>>>(x, W, src, supTp);
  fused_gcn_kernel<<<NNODES / 32, 128, 0, stream>>>(A, supTp, Wd, out);
}